// Round 1
// baseline (1871.679 us; speedup 1.0000x reference)
//
#include <hip/hip_runtime.h>
#include <math.h>

#define N_NODES 100000
#define N_EDGES 500000
#define HC 128

// ---- ordered-float encoding for atomicMax on float (incl. negatives) ----
__device__ __forceinline__ unsigned enc_f(float f) {
    unsigned u = __float_as_uint(f);
    return (u & 0x80000000u) ? ~u : (u | 0x80000000u);
}
__device__ __forceinline__ float dec_f(unsigned e) {
    unsigned b = (e & 0x80000000u) ? (e & 0x7fffffffu) : ~e;
    return __uint_as_float(b);
}

// ---------------------------------------------------------------------------
// K1: fused node projections. out_cols = [Qn | Kn | Vn | out(=Sn)], 512 wide.
// Block = 256 threads = 4 waves. Each block: 32 rows x 512 cols.
// Wave w handles rows w*8..w*8+7 (x reads are wave-uniform LDS broadcasts);
// lane handles 8 consecutive output cols (all within one W matrix).
// ---------------------------------------------------------------------------
__global__ __launch_bounds__(256) void node_proj_kernel(
    const float* __restrict__ x,
    const float* __restrict__ Wq, const float* __restrict__ bq,
    const float* __restrict__ Wk, const float* __restrict__ bk,
    const float* __restrict__ Wv, const float* __restrict__ bv,
    const float* __restrict__ Ws, const float* __restrict__ bs,
    float* __restrict__ Qn, float* __restrict__ Kn, float* __restrict__ Vn,
    float* __restrict__ out)
{
    __shared__ float xs[32 * 128];
    const int t = threadIdx.x;
    const long row0 = (long)blockIdx.x * 32;   // N = 3125 * 32 exactly

    for (int idx = t; idx < 32 * 128; idx += 256)
        xs[idx] = x[row0 * 128 + idx];
    __syncthreads();

    const int rg = t >> 6;        // wave id -> row group
    const int cg = t & 63;        // lane -> col group
    const int j0 = cg * 8;        // global col 0..504
    const int mat = j0 >> 7;      // 0=q 1=k 2=v 3=s
    const int jj = j0 & 127;

    const float* W = (mat == 0) ? Wq : (mat == 1) ? Wk : (mat == 2) ? Wv : Ws;
    const float* b = (mat == 0) ? bq : (mat == 1) ? bk : (mat == 2) ? bv : bs;
    float* dstp    = (mat == 0) ? Qn : (mat == 1) ? Kn : (mat == 2) ? Vn : out;

    float acc[8][8];
#pragma unroll
    for (int r = 0; r < 8; ++r)
#pragma unroll
        for (int j = 0; j < 8; ++j) acc[r][j] = 0.f;

    const float* xrow = &xs[(rg * 8) * 128];
#pragma unroll 2
    for (int c = 0; c < 128; c += 4) {
        float4 xv[8];
#pragma unroll
        for (int r = 0; r < 8; ++r)
            xv[r] = *(const float4*)&xrow[r * 128 + c];
#pragma unroll
        for (int j = 0; j < 8; ++j) {
            float4 wv = *(const float4*)&W[(jj + j) * 128 + c];
#pragma unroll
            for (int r = 0; r < 8; ++r) {
                acc[r][j] = fmaf(xv[r].x, wv.x, acc[r][j]);
                acc[r][j] = fmaf(xv[r].y, wv.y, acc[r][j]);
                acc[r][j] = fmaf(xv[r].z, wv.z, acc[r][j]);
                acc[r][j] = fmaf(xv[r].w, wv.w, acc[r][j]);
            }
        }
    }

    float bv8[8];
#pragma unroll
    for (int j = 0; j < 8; ++j) bv8[j] = b[jj + j];

#pragma unroll
    for (int r = 0; r < 8; ++r) {
        long o = (row0 + rg * 8 + r) * 128 + jj;
        float4 o0 = make_float4(acc[r][0] + bv8[0], acc[r][1] + bv8[1],
                                acc[r][2] + bv8[2], acc[r][3] + bv8[3]);
        float4 o1 = make_float4(acc[r][4] + bv8[4], acc[r][5] + bv8[5],
                                acc[r][6] + bv8[6], acc[r][7] + bv8[7]);
        *(float4*)&dstp[o] = o0;
        *(float4*)&dstp[o + 4] = o1;
    }
}

// ---------------------------------------------------------------------------
// K2: per-edge alpha = q . (k + We@ea) / sqrt(32), global per-head max.
// One wave per edge (grid-stride). We rows (lane, lane+64) live in VGPRs.
// ---------------------------------------------------------------------------
__global__ __launch_bounds__(256) void edge_alpha_kernel(
    const int* __restrict__ ei, const float* __restrict__ ea,
    const float* __restrict__ We,
    const float* __restrict__ Qn, const float* __restrict__ Kn,
    float* __restrict__ alpha, unsigned* __restrict__ m_enc)
{
    const int lane = threadIdx.x & 63;
    const int wid = threadIdx.x >> 6;
    const long wgid = (long)blockIdx.x * 4 + wid;
    const long nwaves = (long)gridDim.x * 4;

    float w0[64], w1[64];
    {
        const float* p0 = &We[lane * 64];
        const float* p1 = &We[(lane + 64) * 64];
#pragma unroll
        for (int c = 0; c < 64; c += 4) {
            float4 a = *(const float4*)&p0[c];
            w0[c] = a.x; w0[c + 1] = a.y; w0[c + 2] = a.z; w0[c + 3] = a.w;
            float4 b4 = *(const float4*)&p1[c];
            w1[c] = b4.x; w1[c + 1] = b4.y; w1[c + 2] = b4.z; w1[c + 3] = b4.w;
        }
    }

    float mx0 = -1e30f, mx1 = -1e30f;
    for (long e = wgid; e < N_EDGES; e += nwaves) {
        const int src = ei[e];
        const int dst = ei[N_EDGES + e];
        const float a0 = ea[e * 64 + lane];
        float e0 = 0.f, e1 = 0.f;
#pragma unroll
        for (int c = 0; c < 64; ++c) {
            const float ac = __shfl(a0, c, 64);
            e0 = fmaf(w0[c], ac, e0);
            e1 = fmaf(w1[c], ac, e1);
        }
        const float q0 = Qn[(long)dst * 128 + lane];
        const float q1 = Qn[(long)dst * 128 + 64 + lane];
        const float k0 = Kn[(long)src * 128 + lane];
        const float k1 = Kn[(long)src * 128 + 64 + lane];
        float p0 = q0 * (k0 + e0);
        float p1 = q1 * (k1 + e1);
#pragma unroll
        for (int off = 1; off < 32; off <<= 1) {
            p0 += __shfl_xor(p0, off, 64);
            p1 += __shfl_xor(p1, off, 64);
        }
        p0 *= 0.17677669529663687f;   // 1/sqrt(32)
        p1 *= 0.17677669529663687f;
        if (lane == 0 || lane == 32) {
            const int h = lane >> 5;
            alpha[e * 4 + h] = p0;
            alpha[e * 4 + 2 + h] = p1;
        }
        mx0 = fmaxf(mx0, p0);
        mx1 = fmaxf(mx1, p1);
    }
    if (lane == 0 || lane == 32) {
        const int h = lane >> 5;
        atomicMax(&m_enc[h], enc_f(mx0));
        atomicMax(&m_enc[2 + h], enc_f(mx1));
    }
}

// ---------------------------------------------------------------------------
// K3: exp(alpha - m) in place + segment-sum denominator over dst.
// ---------------------------------------------------------------------------
__global__ __launch_bounds__(256) void exp_denom_kernel(
    const int* __restrict__ ei, float* __restrict__ alpha,
    const unsigned* __restrict__ m_enc, float* __restrict__ denom)
{
    const int i = blockIdx.x * 256 + threadIdx.x;
    if (i >= N_EDGES * 4) return;
    const int e = i >> 2;
    const int h = i & 3;
    const float m = dec_f(m_enc[h]);
    const float v = expf(alpha[i] - m);
    alpha[i] = v;
    const int dst = ei[N_EDGES + e];
    atomicAdd(&denom[(long)dst * 4 + h], v);
}

// ---------------------------------------------------------------------------
// K4: msg = (Vn[src] + We@ea) * exp_a/(denom[dst]+eps), scatter-add to out.
// ---------------------------------------------------------------------------
__global__ __launch_bounds__(256) void edge_msg_kernel(
    const int* __restrict__ ei, const float* __restrict__ ea,
    const float* __restrict__ We,
    const float* __restrict__ Vn, const float* __restrict__ alpha,
    const float* __restrict__ denom, float* __restrict__ out)
{
    const int lane = threadIdx.x & 63;
    const int wid = threadIdx.x >> 6;
    const long wgid = (long)blockIdx.x * 4 + wid;
    const long nwaves = (long)gridDim.x * 4;

    float w0[64], w1[64];
    {
        const float* p0 = &We[lane * 64];
        const float* p1 = &We[(lane + 64) * 64];
#pragma unroll
        for (int c = 0; c < 64; c += 4) {
            float4 a = *(const float4*)&p0[c];
            w0[c] = a.x; w0[c + 1] = a.y; w0[c + 2] = a.z; w0[c + 3] = a.w;
            float4 b4 = *(const float4*)&p1[c];
            w1[c] = b4.x; w1[c + 1] = b4.y; w1[c + 2] = b4.z; w1[c + 3] = b4.w;
        }
    }

    for (long e = wgid; e < N_EDGES; e += nwaves) {
        const int src = ei[e];
        const int dst = ei[N_EDGES + e];
        const float a0 = ea[e * 64 + lane];
        float e0 = 0.f, e1 = 0.f;
#pragma unroll
        for (int c = 0; c < 64; ++c) {
            const float ac = __shfl(a0, c, 64);
            e0 = fmaf(w0[c], ac, e0);
            e1 = fmaf(w1[c], ac, e1);
        }
        const float v0 = Vn[(long)src * 128 + lane];
        const float v1 = Vn[(long)src * 128 + 64 + lane];
        const int h0 = lane >> 5;
        const float ex0 = alpha[e * 4 + h0];
        const float ex1 = alpha[e * 4 + 2 + h0];
        const float d0 = denom[(long)dst * 4 + h0];
        const float d1 = denom[(long)dst * 4 + 2 + h0];
        const float an0 = ex0 / (d0 + 1e-16f);
        const float an1 = ex1 / (d1 + 1e-16f);
        atomicAdd(&out[(long)dst * 128 + lane], (v0 + e0) * an0);
        atomicAdd(&out[(long)dst * 128 + 64 + lane], (v1 + e1) * an1);
    }
}

// ---------------------------------------------------------------------------
// Workspace layout (floats):
//   Qn    [N,128]  @ 0          (12,800,000)
//   Kn    [N,128]  @ 12,800,000
//   Vn    [N,128]  @ 25,600,000
//   alpha [E,4]    @ 38,400,000 ( 2,000,000)
//   denom [N,4]    @ 40,400,000 (   400,000)
//   m_enc [4]      @ 40,800,000
// total ~163.2 MB
// ---------------------------------------------------------------------------
extern "C" void kernel_launch(void* const* d_in, const int* in_sizes, int n_in,
                              void* d_out, int out_size, void* d_ws, size_t ws_size,
                              hipStream_t stream)
{
    const float* x  = (const float*)d_in[0];
    const int*   ei = (const int*)d_in[1];
    const float* ea = (const float*)d_in[2];
    const float* Wq = (const float*)d_in[3];
    const float* bq = (const float*)d_in[4];
    const float* Wk = (const float*)d_in[5];
    const float* bk = (const float*)d_in[6];
    const float* Wv = (const float*)d_in[7];
    const float* bv = (const float*)d_in[8];
    const float* We = (const float*)d_in[9];
    const float* Ws = (const float*)d_in[10];
    const float* bs = (const float*)d_in[11];
    float* out = (float*)d_out;

    float* ws    = (float*)d_ws;
    float* Qn    = ws;
    float* Kn    = ws + 12800000;
    float* Vn    = ws + 25600000;
    float* alpha = ws + 38400000;
    float* denom = ws + 40400000;
    unsigned* m_enc = (unsigned*)(ws + 40800000);

    // zero denom + m_enc (contiguous)
    hipMemsetAsync(denom, 0, (400000 + 4) * sizeof(float), stream);

    node_proj_kernel<<<3125, 256, 0, stream>>>(x, Wq, bq, Wk, bk, Wv, bv, Ws, bs,
                                               Qn, Kn, Vn, out);
    edge_alpha_kernel<<<2048, 256, 0, stream>>>(ei, ea, We, Qn, Kn, alpha, m_enc);
    exp_denom_kernel<<<(N_EDGES * 4 + 255) / 256, 256, 0, stream>>>(ei, alpha, m_enc, denom);
    edge_msg_kernel<<<2048, 256, 0, stream>>>(ei, ea, We, Vn, alpha, denom, out);
}

// Round 2
// 1170.010 us; speedup vs baseline: 1.5997x; 1.5997x over previous
//
#include <hip/hip_runtime.h>
#include <hip/hip_bf16.h>
#include <math.h>

#define N_NODES 100000
#define N_EDGES 500000
#define HC 128

// ---- ordered-float encoding for atomicMax on float (incl. negatives) ----
__device__ __forceinline__ unsigned enc_f(float f) {
    unsigned u = __float_as_uint(f);
    return (u & 0x80000000u) ? ~u : (u | 0x80000000u);
}
__device__ __forceinline__ float dec_f(unsigned e) {
    unsigned b = (e & 0x80000000u) ? (e & 0x7fffffffu) : ~e;
    return __uint_as_float(b);
}

// ---------------------------------------------------------------------------
// K1 v2: LDS-tiled fp32 GEMM. C[100000,512] = x[100000,128] @ Wcat[512,128]^T
// Block tile: 128 rows x 128 cols (one W matrix per col-block), K-chunks of 32.
// Thread micro-tile 8x8: rows ty*8+i, cols tx+16*j (strided cols ->
// conflict-free LDS reads: bank = (tx + ...) distinct across the 16 tx lanes,
// ty-broadcast is same-address = free).
// ---------------------------------------------------------------------------
__global__ __launch_bounds__(256) void node_proj_kernel(
    const float* __restrict__ x,
    const float* __restrict__ Wq, const float* __restrict__ bq,
    const float* __restrict__ Wk, const float* __restrict__ bk,
    const float* __restrict__ Wv, const float* __restrict__ bv,
    const float* __restrict__ Ws, const float* __restrict__ bs,
    float* __restrict__ Qn, float* __restrict__ Kn, float* __restrict__ Vn,
    float* __restrict__ out)
{
    __shared__ float xs[128][33];   // rows x k-chunk, stride 33 -> rows 8 apart hit distinct banks
    __shared__ float wt[128][33];   // cols x k-chunk

    const int t = threadIdx.x;
    const int rb = blockIdx.x >> 2;
    const int cb = blockIdx.x & 3;
    const long r0 = (long)rb * 128;

    const float* W    = (cb == 0) ? Wq : (cb == 1) ? Wk : (cb == 2) ? Wv : Ws;
    const float* bias = (cb == 0) ? bq : (cb == 1) ? bk : (cb == 2) ? bv : bs;
    float* dstp       = (cb == 0) ? Qn : (cb == 1) ? Kn : (cb == 2) ? Vn : out;

    const int tx = t & 15;
    const int ty = t >> 4;

    float acc[8][8];
#pragma unroll
    for (int i = 0; i < 8; ++i)
#pragma unroll
        for (int j = 0; j < 8; ++j) acc[i][j] = 0.f;

    for (int kc = 0; kc < 128; kc += 32) {
        for (int i = t; i < 128 * 32; i += 256) {
            const int r = i >> 5, c = i & 31;
            const long row = r0 + r;
            xs[r][c] = (row < N_NODES) ? x[row * 128 + kc + c] : 0.f;
            wt[r][c] = W[r * 128 + kc + c];
        }
        __syncthreads();
#pragma unroll 8
        for (int k = 0; k < 32; ++k) {
            float a[8], b[8];
#pragma unroll
            for (int i = 0; i < 8; ++i) a[i] = xs[ty * 8 + i][k];
#pragma unroll
            for (int j = 0; j < 8; ++j) b[j] = wt[tx + 16 * j][k];
#pragma unroll
            for (int i = 0; i < 8; ++i)
#pragma unroll
                for (int j = 0; j < 8; ++j)
                    acc[i][j] = fmaf(a[i], b[j], acc[i][j]);
        }
        __syncthreads();
    }

    float bv8[8];
#pragma unroll
    for (int j = 0; j < 8; ++j) bv8[j] = bias[tx + 16 * j];

#pragma unroll
    for (int i = 0; i < 8; ++i) {
        const long row = r0 + ty * 8 + i;
        if (row < N_NODES) {
#pragma unroll
            for (int j = 0; j < 8; ++j)
                dstp[row * 128 + tx + 16 * j] = acc[i][j] + bv8[j];
        }
    }
}

// ---------------------------------------------------------------------------
// K1b: Ee[e,ch] = sum_c ea[e,c] * We[ch,c], stored bf16. Tile 128 edges x
// 128 ch; We staged full-K once, ea in K-chunks of 32.
// ---------------------------------------------------------------------------
__global__ __launch_bounds__(256) void ee_gemm_kernel(
    const float* __restrict__ ea, const float* __restrict__ We,
    __hip_bfloat16* __restrict__ Ee)
{
    __shared__ float wes[128][65];  // ch x k (full K=64), stride 65
    __shared__ float eas[128][33];  // edge x k-chunk

    const int t = threadIdx.x;
    const long e0 = (long)blockIdx.x * 128;

    for (int i = t; i < 128 * 64; i += 256) {
        const int r = i >> 6, c = i & 63;
        wes[r][c] = We[i];
    }

    const int tx = t & 15;
    const int ty = t >> 4;

    float acc[8][8];
#pragma unroll
    for (int i = 0; i < 8; ++i)
#pragma unroll
        for (int j = 0; j < 8; ++j) acc[i][j] = 0.f;

    for (int kc = 0; kc < 64; kc += 32) {
        __syncthreads();
        for (int i = t; i < 128 * 32; i += 256) {
            const int r = i >> 5, c = i & 31;
            const long e = e0 + r;
            eas[r][c] = (e < N_EDGES) ? ea[e * 64 + kc + c] : 0.f;
        }
        __syncthreads();
#pragma unroll 8
        for (int k = 0; k < 32; ++k) {
            float a[8], b[8];
#pragma unroll
            for (int i = 0; i < 8; ++i) a[i] = eas[ty * 8 + i][k];
#pragma unroll
            for (int j = 0; j < 8; ++j) b[j] = wes[tx + 16 * j][kc + k];
#pragma unroll
            for (int i = 0; i < 8; ++i)
#pragma unroll
                for (int j = 0; j < 8; ++j)
                    acc[i][j] = fmaf(a[i], b[j], acc[i][j]);
        }
    }

#pragma unroll
    for (int i = 0; i < 8; ++i) {
        const long e = e0 + ty * 8 + i;
        if (e < N_EDGES) {
#pragma unroll
            for (int j = 0; j < 8; ++j)
                Ee[e * 128 + tx + 16 * j] = __float2bfloat16(acc[i][j]);
        }
    }
}

// ---------------------------------------------------------------------------
// K2 v2: alpha = q.(k+e)/sqrt(32) with e read from precomputed Ee (bf16).
// One wave per edge, grid-stride; low VGPR -> high occupancy.
// ---------------------------------------------------------------------------
__global__ __launch_bounds__(256) void edge_alpha2_kernel(
    const int* __restrict__ ei, const __hip_bfloat16* __restrict__ Ee,
    const float* __restrict__ Qn, const float* __restrict__ Kn,
    float* __restrict__ alpha, unsigned* __restrict__ m_enc)
{
    const int lane = threadIdx.x & 63;
    const int wid = threadIdx.x >> 6;
    const long wgid = (long)blockIdx.x * 4 + wid;
    const long nwaves = (long)gridDim.x * 4;

    float mx0 = -1e30f, mx1 = -1e30f;
    for (long e = wgid; e < N_EDGES; e += nwaves) {
        const int src = ei[e];
        const int dst = ei[N_EDGES + e];
        const float e0 = __bfloat162float(Ee[e * 128 + lane]);
        const float e1 = __bfloat162float(Ee[e * 128 + 64 + lane]);
        const float q0 = Qn[(long)dst * 128 + lane];
        const float q1 = Qn[(long)dst * 128 + 64 + lane];
        const float k0 = Kn[(long)src * 128 + lane];
        const float k1 = Kn[(long)src * 128 + 64 + lane];
        float p0 = q0 * (k0 + e0);
        float p1 = q1 * (k1 + e1);
#pragma unroll
        for (int off = 1; off < 32; off <<= 1) {
            p0 += __shfl_xor(p0, off, 64);
            p1 += __shfl_xor(p1, off, 64);
        }
        p0 *= 0.17677669529663687f;
        p1 *= 0.17677669529663687f;
        if (lane == 0 || lane == 32) {
            const int h = lane >> 5;
            alpha[e * 4 + h] = p0;
            alpha[e * 4 + 2 + h] = p1;
        }
        mx0 = fmaxf(mx0, p0);
        mx1 = fmaxf(mx1, p1);
    }
    if (lane == 0 || lane == 32) {
        const int h = lane >> 5;
        atomicMax(&m_enc[h], enc_f(mx0));
        atomicMax(&m_enc[2 + h], enc_f(mx1));
    }
}

// ---------------------------------------------------------------------------
// K3: exp(alpha - m) in place + segment-sum denominator over dst. (unchanged)
// ---------------------------------------------------------------------------
__global__ __launch_bounds__(256) void exp_denom_kernel(
    const int* __restrict__ ei, float* __restrict__ alpha,
    const unsigned* __restrict__ m_enc, float* __restrict__ denom)
{
    const int i = blockIdx.x * 256 + threadIdx.x;
    if (i >= N_EDGES * 4) return;
    const int e = i >> 2;
    const int h = i & 3;
    const float m = dec_f(m_enc[h]);
    const float v = expf(alpha[i] - m);
    alpha[i] = v;
    const int dst = ei[N_EDGES + e];
    atomicAdd(&denom[(long)dst * 4 + h], v);
}

// ---------------------------------------------------------------------------
// K4 v2: msg = (Vn[src] + Ee) * exp_a/(denom[dst]+eps), scatter-add to out.
// ---------------------------------------------------------------------------
__global__ __launch_bounds__(256) void edge_msg2_kernel(
    const int* __restrict__ ei, const __hip_bfloat16* __restrict__ Ee,
    const float* __restrict__ Vn, const float* __restrict__ alpha,
    const float* __restrict__ denom, float* __restrict__ out)
{
    const int lane = threadIdx.x & 63;
    const int wid = threadIdx.x >> 6;
    const long wgid = (long)blockIdx.x * 4 + wid;
    const long nwaves = (long)gridDim.x * 4;

    for (long e = wgid; e < N_EDGES; e += nwaves) {
        const int src = ei[e];
        const int dst = ei[N_EDGES + e];
        const float e0 = __bfloat162float(Ee[e * 128 + lane]);
        const float e1 = __bfloat162float(Ee[e * 128 + 64 + lane]);
        const float v0 = Vn[(long)src * 128 + lane];
        const float v1 = Vn[(long)src * 128 + 64 + lane];
        const int h0 = lane >> 5;
        const float ex0 = alpha[e * 4 + h0];
        const float ex1 = alpha[e * 4 + 2 + h0];
        const float d0 = denom[(long)dst * 4 + h0];
        const float d1 = denom[(long)dst * 4 + 2 + h0];
        const float an0 = ex0 / (d0 + 1e-16f);
        const float an1 = ex1 / (d1 + 1e-16f);
        atomicAdd(&out[(long)dst * 128 + lane], (v0 + e0) * an0);
        atomicAdd(&out[(long)dst * 128 + 64 + lane], (v1 + e1) * an1);
    }
}

// ---------------------------------------------------------------------------
// Fallback K2/K4 (shfl-based We@ea recompute) for small workspaces.
// ---------------------------------------------------------------------------
__global__ __launch_bounds__(256) void edge_alpha_kernel(
    const int* __restrict__ ei, const float* __restrict__ ea,
    const float* __restrict__ We,
    const float* __restrict__ Qn, const float* __restrict__ Kn,
    float* __restrict__ alpha, unsigned* __restrict__ m_enc)
{
    const int lane = threadIdx.x & 63;
    const int wid = threadIdx.x >> 6;
    const long wgid = (long)blockIdx.x * 4 + wid;
    const long nwaves = (long)gridDim.x * 4;

    float w0[64], w1[64];
    {
        const float* p0 = &We[lane * 64];
        const float* p1 = &We[(lane + 64) * 64];
#pragma unroll
        for (int c = 0; c < 64; c += 4) {
            float4 a = *(const float4*)&p0[c];
            w0[c] = a.x; w0[c + 1] = a.y; w0[c + 2] = a.z; w0[c + 3] = a.w;
            float4 b4 = *(const float4*)&p1[c];
            w1[c] = b4.x; w1[c + 1] = b4.y; w1[c + 2] = b4.z; w1[c + 3] = b4.w;
        }
    }

    float mx0 = -1e30f, mx1 = -1e30f;
    for (long e = wgid; e < N_EDGES; e += nwaves) {
        const int src = ei[e];
        const int dst = ei[N_EDGES + e];
        const float a0 = ea[e * 64 + lane];
        float e0 = 0.f, e1 = 0.f;
#pragma unroll
        for (int c = 0; c < 64; ++c) {
            const float ac = __shfl(a0, c, 64);
            e0 = fmaf(w0[c], ac, e0);
            e1 = fmaf(w1[c], ac, e1);
        }
        const float q0 = Qn[(long)dst * 128 + lane];
        const float q1 = Qn[(long)dst * 128 + 64 + lane];
        const float k0 = Kn[(long)src * 128 + lane];
        const float k1 = Kn[(long)src * 128 + 64 + lane];
        float p0 = q0 * (k0 + e0);
        float p1 = q1 * (k1 + e1);
#pragma unroll
        for (int off = 1; off < 32; off <<= 1) {
            p0 += __shfl_xor(p0, off, 64);
            p1 += __shfl_xor(p1, off, 64);
        }
        p0 *= 0.17677669529663687f;
        p1 *= 0.17677669529663687f;
        if (lane == 0 || lane == 32) {
            const int h = lane >> 5;
            alpha[e * 4 + h] = p0;
            alpha[e * 4 + 2 + h] = p1;
        }
        mx0 = fmaxf(mx0, p0);
        mx1 = fmaxf(mx1, p1);
    }
    if (lane == 0 || lane == 32) {
        const int h = lane >> 5;
        atomicMax(&m_enc[h], enc_f(mx0));
        atomicMax(&m_enc[2 + h], enc_f(mx1));
    }
}

__global__ __launch_bounds__(256) void edge_msg_kernel(
    const int* __restrict__ ei, const float* __restrict__ ea,
    const float* __restrict__ We,
    const float* __restrict__ Vn, const float* __restrict__ alpha,
    const float* __restrict__ denom, float* __restrict__ out)
{
    const int lane = threadIdx.x & 63;
    const int wid = threadIdx.x >> 6;
    const long wgid = (long)blockIdx.x * 4 + wid;
    const long nwaves = (long)gridDim.x * 4;

    float w0[64], w1[64];
    {
        const float* p0 = &We[lane * 64];
        const float* p1 = &We[(lane + 64) * 64];
#pragma unroll
        for (int c = 0; c < 64; c += 4) {
            float4 a = *(const float4*)&p0[c];
            w0[c] = a.x; w0[c + 1] = a.y; w0[c + 2] = a.z; w0[c + 3] = a.w;
            float4 b4 = *(const float4*)&p1[c];
            w1[c] = b4.x; w1[c + 1] = b4.y; w1[c + 2] = b4.z; w1[c + 3] = b4.w;
        }
    }

    for (long e = wgid; e < N_EDGES; e += nwaves) {
        const int src = ei[e];
        const int dst = ei[N_EDGES + e];
        const float a0 = ea[e * 64 + lane];
        float e0 = 0.f, e1 = 0.f;
#pragma unroll
        for (int c = 0; c < 64; ++c) {
            const float ac = __shfl(a0, c, 64);
            e0 = fmaf(w0[c], ac, e0);
            e1 = fmaf(w1[c], ac, e1);
        }
        const float v0 = Vn[(long)src * 128 + lane];
        const float v1 = Vn[(long)src * 128 + 64 + lane];
        const int h0 = lane >> 5;
        const float ex0 = alpha[e * 4 + h0];
        const float ex1 = alpha[e * 4 + 2 + h0];
        const float d0 = denom[(long)dst * 4 + h0];
        const float d1 = denom[(long)dst * 4 + 2 + h0];
        const float an0 = ex0 / (d0 + 1e-16f);
        const float an1 = ex1 / (d1 + 1e-16f);
        atomicAdd(&out[(long)dst * 128 + lane], (v0 + e0) * an0);
        atomicAdd(&out[(long)dst * 128 + 64 + lane], (v1 + e1) * an1);
    }
}

// ---------------------------------------------------------------------------
// Workspace layout (float offsets):
//   Qn    [N,128]  @ 0
//   Kn    [N,128]  @ 12,800,000
//   Vn    [N,128]  @ 25,600,000
//   alpha [E,4]    @ 38,400,000
//   denom [N,4]    @ 40,400,000
//   m_enc [4]      @ 40,800,000
//   Ee bf16 [E,128]@ byte 163,200,032  (+128 MB, only if ws_size allows)
// ---------------------------------------------------------------------------
extern "C" void kernel_launch(void* const* d_in, const int* in_sizes, int n_in,
                              void* d_out, int out_size, void* d_ws, size_t ws_size,
                              hipStream_t stream)
{
    const float* x  = (const float*)d_in[0];
    const int*   ei = (const int*)d_in[1];
    const float* ea = (const float*)d_in[2];
    const float* Wq = (const float*)d_in[3];
    const float* bq = (const float*)d_in[4];
    const float* Wk = (const float*)d_in[5];
    const float* bk = (const float*)d_in[6];
    const float* Wv = (const float*)d_in[7];
    const float* bv = (const float*)d_in[8];
    const float* We = (const float*)d_in[9];
    const float* Ws = (const float*)d_in[10];
    const float* bs = (const float*)d_in[11];
    float* out = (float*)d_out;

    float* ws    = (float*)d_ws;
    float* Qn    = ws;
    float* Kn    = ws + 12800000;
    float* Vn    = ws + 25600000;
    float* alpha = ws + 38400000;
    float* denom = ws + 40400000;
    unsigned* m_enc = (unsigned*)(ws + 40800000);
    const size_t base_bytes = (size_t)40800004 * 4;   // 163,200,016
    __hip_bfloat16* Ee = (__hip_bfloat16*)((char*)d_ws + 163200032);
    const size_t need_ee = 163200032 + (size_t)N_EDGES * 128 * 2;  // 291.2 MB
    const bool use_ee = (ws_size >= need_ee);
    (void)base_bytes;

    hipMemsetAsync(denom, 0, (400000 + 4) * sizeof(float), stream);

    node_proj_kernel<<<782 * 4, 256, 0, stream>>>(x, Wq, bq, Wk, bk, Wv, bv, Ws, bs,
                                                  Qn, Kn, Vn, out);
    if (use_ee) {
        ee_gemm_kernel<<<(N_EDGES + 127) / 128, 256, 0, stream>>>(ea, We, Ee);
        edge_alpha2_kernel<<<2048, 256, 0, stream>>>(ei, Ee, Qn, Kn, alpha, m_enc);
    } else {
        edge_alpha_kernel<<<2048, 256, 0, stream>>>(ei, ea, We, Qn, Kn, alpha, m_enc);
    }
    exp_denom_kernel<<<(N_EDGES * 4 + 255) / 256, 256, 0, stream>>>(ei, alpha, m_enc, denom);
    if (use_ee) {
        edge_msg2_kernel<<<2048, 256, 0, stream>>>(ei, Ee, Vn, alpha, denom, out);
    } else {
        edge_msg_kernel<<<2048, 256, 0, stream>>>(ei, ea, We, Vn, alpha, denom, out);
    }
}

// Round 3
// 966.666 us; speedup vs baseline: 1.9362x; 1.2104x over previous
//
#include <hip/hip_runtime.h>
#include <hip/hip_bf16.h>
#include <math.h>

#define N_NODES 100000
#define N_EDGES 500000
#define M0 8.0f
#define INV_SQRT32 0.17677669529663687f

static __device__ __forceinline__ unsigned short f2bf(float f) {
    __hip_bfloat16 h = __float2bfloat16(f);
    return *(unsigned short*)&h;
}

// ---------------------------------------------------------------------------
// K1 v3: LDS-tiled fp32 GEMM, transposed LDS for vectorized ds_read_b128.
// C[100000,512] = x[100000,128] @ Wcat[512,128]^T. Block: 128 rows x 128 cols
// (one W matrix per cb). Thread micro-tile 8x8: rows ty*8+i, cols tx*4+j and
// 64+tx*4+j. LDS layout [k][row] stride 132: a-reads broadcast over tx,
// 4 distinct ty banks; b-reads 2-way alias over tx (free per m136).
// ---------------------------------------------------------------------------
__global__ __launch_bounds__(256) void node_proj_kernel(
    const float* __restrict__ x,
    const float* __restrict__ Wq, const float* __restrict__ bq,
    const float* __restrict__ Wk, const float* __restrict__ bk,
    const float* __restrict__ Wv, const float* __restrict__ bv,
    const float* __restrict__ Ws, const float* __restrict__ bs,
    float* __restrict__ Qn, float* __restrict__ Kn, float* __restrict__ Vn,
    float* __restrict__ out)
{
    __shared__ float xsT[32][132];
    __shared__ float wtT[32][132];

    const int t = threadIdx.x;
    const int rb = blockIdx.x >> 2;
    const int cb = blockIdx.x & 3;
    const long r0 = (long)rb * 128;

    const float* W    = (cb == 0) ? Wq : (cb == 1) ? Wk : (cb == 2) ? Wv : Ws;
    const float* bias = (cb == 0) ? bq : (cb == 1) ? bk : (cb == 2) ? bv : bs;
    float* dstp       = (cb == 0) ? Qn : (cb == 1) ? Kn : (cb == 2) ? Vn : out;

    const int tx = t & 15;
    const int ty = t >> 4;

    float acc[8][8];
#pragma unroll
    for (int i = 0; i < 8; ++i)
#pragma unroll
        for (int j = 0; j < 8; ++j) acc[i][j] = 0.f;

    for (int kc = 0; kc < 128; kc += 32) {
        __syncthreads();
        for (int i = t; i < 1024; i += 256) {
            const int r = i >> 3;            // 0..127
            const int c4 = (i & 7) * 4;      // 0..28
            const long row = r0 + r;
            float4 xv = (row < N_NODES) ? *(const float4*)&x[row * 128 + kc + c4]
                                        : make_float4(0.f, 0.f, 0.f, 0.f);
            xsT[c4 + 0][r] = xv.x; xsT[c4 + 1][r] = xv.y;
            xsT[c4 + 2][r] = xv.z; xsT[c4 + 3][r] = xv.w;
            float4 wv = *(const float4*)&W[r * 128 + kc + c4];
            wtT[c4 + 0][r] = wv.x; wtT[c4 + 1][r] = wv.y;
            wtT[c4 + 2][r] = wv.z; wtT[c4 + 3][r] = wv.w;
        }
        __syncthreads();
#pragma unroll 4
        for (int k = 0; k < 32; ++k) {
            const float4 a0 = *(const float4*)&xsT[k][ty * 8];
            const float4 a1 = *(const float4*)&xsT[k][ty * 8 + 4];
            const float4 b0 = *(const float4*)&wtT[k][tx * 4];
            const float4 b1 = *(const float4*)&wtT[k][64 + tx * 4];
            const float a[8] = {a0.x, a0.y, a0.z, a0.w, a1.x, a1.y, a1.z, a1.w};
            const float b[8] = {b0.x, b0.y, b0.z, b0.w, b1.x, b1.y, b1.z, b1.w};
#pragma unroll
            for (int i = 0; i < 8; ++i)
#pragma unroll
                for (int j = 0; j < 8; ++j)
                    acc[i][j] = fmaf(a[i], b[j], acc[i][j]);
        }
    }

    float bias0[4], bias1[4];
#pragma unroll
    for (int j = 0; j < 4; ++j) {
        bias0[j] = bias[tx * 4 + j];
        bias1[j] = bias[64 + tx * 4 + j];
    }

#pragma unroll
    for (int i = 0; i < 8; ++i) {
        const long row = r0 + ty * 8 + i;
        if (row < N_NODES) {
            float4 o0 = make_float4(acc[i][0] + bias0[0], acc[i][1] + bias0[1],
                                    acc[i][2] + bias0[2], acc[i][3] + bias0[3]);
            float4 o1 = make_float4(acc[i][4] + bias1[0], acc[i][5] + bias1[1],
                                    acc[i][6] + bias1[2], acc[i][7] + bias1[3]);
            *(float4*)&dstp[row * 128 + tx * 4] = o0;
            *(float4*)&dstp[row * 128 + 64 + tx * 4] = o1;
        }
    }
}

// ---------------------------------------------------------------------------
// K1b v2: Ee[e,ch] = ea[e,:] . We[ch,:], bf16 out. Same transposed-LDS scheme,
// K=64 in two chunks of 32. Tile 128 edges x 128 ch.
// ---------------------------------------------------------------------------
__global__ __launch_bounds__(256) void ee_gemm_kernel(
    const float* __restrict__ ea, const float* __restrict__ We,
    unsigned short* __restrict__ Ee)
{
    __shared__ float easT[32][132];
    __shared__ float wesT[32][132];

    const int t = threadIdx.x;
    const long e0 = (long)blockIdx.x * 128;
    const int tx = t & 15;
    const int ty = t >> 4;

    float acc[8][8];
#pragma unroll
    for (int i = 0; i < 8; ++i)
#pragma unroll
        for (int j = 0; j < 8; ++j) acc[i][j] = 0.f;

    for (int kc = 0; kc < 64; kc += 32) {
        __syncthreads();
        for (int i = t; i < 1024; i += 256) {
            const int r = i >> 3;
            const int c4 = (i & 7) * 4;
            const long e = e0 + r;
            float4 av = (e < N_EDGES) ? *(const float4*)&ea[e * 64 + kc + c4]
                                      : make_float4(0.f, 0.f, 0.f, 0.f);
            easT[c4 + 0][r] = av.x; easT[c4 + 1][r] = av.y;
            easT[c4 + 2][r] = av.z; easT[c4 + 3][r] = av.w;
            float4 wv = *(const float4*)&We[r * 64 + kc + c4];
            wesT[c4 + 0][r] = wv.x; wesT[c4 + 1][r] = wv.y;
            wesT[c4 + 2][r] = wv.z; wesT[c4 + 3][r] = wv.w;
        }
        __syncthreads();
#pragma unroll 4
        for (int k = 0; k < 32; ++k) {
            const float4 a0 = *(const float4*)&easT[k][ty * 8];
            const float4 a1 = *(const float4*)&easT[k][ty * 8 + 4];
            const float4 b0 = *(const float4*)&wesT[k][tx * 4];
            const float4 b1 = *(const float4*)&wesT[k][64 + tx * 4];
            const float a[8] = {a0.x, a0.y, a0.z, a0.w, a1.x, a1.y, a1.z, a1.w};
            const float b[8] = {b0.x, b0.y, b0.z, b0.w, b1.x, b1.y, b1.z, b1.w};
#pragma unroll
            for (int i = 0; i < 8; ++i)
#pragma unroll
                for (int j = 0; j < 8; ++j)
                    acc[i][j] = fmaf(a[i], b[j], acc[i][j]);
        }
    }

#pragma unroll
    for (int i = 0; i < 8; ++i) {
        const long e = e0 + ty * 8 + i;
        if (e < N_EDGES) {
            ushort4 u0, u1;
            u0.x = f2bf(acc[i][0]); u0.y = f2bf(acc[i][1]);
            u0.z = f2bf(acc[i][2]); u0.w = f2bf(acc[i][3]);
            u1.x = f2bf(acc[i][4]); u1.y = f2bf(acc[i][5]);
            u1.z = f2bf(acc[i][6]); u1.w = f2bf(acc[i][7]);
            *(ushort4*)&Ee[e * 128 + tx * 4] = u0;
            *(ushort4*)&Ee[e * 128 + 64 + tx * 4] = u1;
        }
    }
}

// ---------------------------------------------------------------------------
// K2 v3 (fused exp+denom): lane handles channels {2l,2l+1}; head h = l>>4.
// exp(p/sqrt(32) - M0) with fixed M0 (global max cancels in the normalize,
// residual ~1e-12 from the +1e-16 term). 2-edge unroll for MLP.
// ---------------------------------------------------------------------------
__global__ __launch_bounds__(256) void edge_alpha_kernel(
    const int* __restrict__ ei, const unsigned short* __restrict__ Ee,
    const float* __restrict__ Qn, const float* __restrict__ Kn,
    float* __restrict__ alpha, float* __restrict__ denom)
{
    const int lane = threadIdx.x & 63;
    const int l2 = lane * 2;
    const int h = lane >> 4;
    const long w = (long)blockIdx.x * 4 + (threadIdx.x >> 6);
    const long nw = (long)gridDim.x * 4;
    const long per = (N_EDGES + nw - 1) / nw;
    long e = w * per;
    const long e1 = (e + per < N_EDGES) ? (e + per) : N_EDGES;

    for (; e + 1 < e1; e += 2) {
        const int s0 = ei[e], s1 = ei[e + 1];
        const int d0 = ei[N_EDGES + e], d1 = ei[N_EDGES + e + 1];
        const unsigned u0 = *(const unsigned*)&Ee[e * 128 + l2];
        const unsigned u1 = *(const unsigned*)&Ee[(e + 1) * 128 + l2];
        const float2 q0 = *(const float2*)&Qn[(long)d0 * 128 + l2];
        const float2 q1 = *(const float2*)&Qn[(long)d1 * 128 + l2];
        const float2 k0 = *(const float2*)&Kn[(long)s0 * 128 + l2];
        const float2 k1 = *(const float2*)&Kn[(long)s1 * 128 + l2];
        const float e0a = __uint_as_float(u0 << 16);
        const float e0b = __uint_as_float(u0 & 0xffff0000u);
        const float e1a = __uint_as_float(u1 << 16);
        const float e1b = __uint_as_float(u1 & 0xffff0000u);
        float p0 = q0.x * (k0.x + e0a) + q0.y * (k0.y + e0b);
        float p1 = q1.x * (k1.x + e1a) + q1.y * (k1.y + e1b);
#pragma unroll
        for (int off = 1; off < 16; off <<= 1) {
            p0 += __shfl_xor(p0, off, 64);
            p1 += __shfl_xor(p1, off, 64);
        }
        p0 = __expf(p0 * INV_SQRT32 - M0);
        p1 = __expf(p1 * INV_SQRT32 - M0);
        if ((lane & 15) == 0) {
            alpha[e * 4 + h] = p0;
            alpha[(e + 1) * 4 + h] = p1;
            atomicAdd(&denom[(long)d0 * 4 + h], p0);
            atomicAdd(&denom[(long)d1 * 4 + h], p1);
        }
    }
    for (; e < e1; ++e) {
        const int s0 = ei[e];
        const int d0 = ei[N_EDGES + e];
        const unsigned u0 = *(const unsigned*)&Ee[e * 128 + l2];
        const float2 q0 = *(const float2*)&Qn[(long)d0 * 128 + l2];
        const float2 k0 = *(const float2*)&Kn[(long)s0 * 128 + l2];
        const float e0a = __uint_as_float(u0 << 16);
        const float e0b = __uint_as_float(u0 & 0xffff0000u);
        float p0 = q0.x * (k0.x + e0a) + q0.y * (k0.y + e0b);
#pragma unroll
        for (int off = 1; off < 16; off <<= 1)
            p0 += __shfl_xor(p0, off, 64);
        p0 = __expf(p0 * INV_SQRT32 - M0);
        if ((lane & 15) == 0) {
            alpha[e * 4 + h] = p0;
            atomicAdd(&denom[(long)d0 * 4 + h], p0);
        }
    }
}

// ---------------------------------------------------------------------------
// K4 v3: msg = (Vn[src]+Ee) * exp_a/(denom[dst]+eps) scatter-add. Same
// 2-ch/lane layout, 2-edge unroll.
// ---------------------------------------------------------------------------
__global__ __launch_bounds__(256) void edge_msg_kernel(
    const int* __restrict__ ei, const unsigned short* __restrict__ Ee,
    const float* __restrict__ Vn, const float* __restrict__ alpha,
    const float* __restrict__ denom, float* __restrict__ out)
{
    const int lane = threadIdx.x & 63;
    const int l2 = lane * 2;
    const int h = lane >> 4;
    const long w = (long)blockIdx.x * 4 + (threadIdx.x >> 6);
    const long nw = (long)gridDim.x * 4;
    const long per = (N_EDGES + nw - 1) / nw;
    long e = w * per;
    const long e1 = (e + per < N_EDGES) ? (e + per) : N_EDGES;

    for (; e + 1 < e1; e += 2) {
        const int s0 = ei[e], s1 = ei[e + 1];
        const int d0 = ei[N_EDGES + e], d1 = ei[N_EDGES + e + 1];
        const unsigned u0 = *(const unsigned*)&Ee[e * 128 + l2];
        const unsigned u1 = *(const unsigned*)&Ee[(e + 1) * 128 + l2];
        const float2 v0 = *(const float2*)&Vn[(long)s0 * 128 + l2];
        const float2 v1 = *(const float2*)&Vn[(long)s1 * 128 + l2];
        const float a0 = alpha[e * 4 + h];
        const float a1 = alpha[(e + 1) * 4 + h];
        const float dn0 = denom[(long)d0 * 4 + h];
        const float dn1 = denom[(long)d1 * 4 + h];
        const float an0 = a0 / (dn0 + 1e-16f);
        const float an1 = a1 / (dn1 + 1e-16f);
        const float e0a = __uint_as_float(u0 << 16);
        const float e0b = __uint_as_float(u0 & 0xffff0000u);
        const float e1a = __uint_as_float(u1 << 16);
        const float e1b = __uint_as_float(u1 & 0xffff0000u);
        atomicAdd(&out[(long)d0 * 128 + l2],     (v0.x + e0a) * an0);
        atomicAdd(&out[(long)d0 * 128 + l2 + 1], (v0.y + e0b) * an0);
        atomicAdd(&out[(long)d1 * 128 + l2],     (v1.x + e1a) * an1);
        atomicAdd(&out[(long)d1 * 128 + l2 + 1], (v1.y + e1b) * an1);
    }
    for (; e < e1; ++e) {
        const int s0 = ei[e];
        const int d0 = ei[N_EDGES + e];
        const unsigned u0 = *(const unsigned*)&Ee[e * 128 + l2];
        const float2 v0 = *(const float2*)&Vn[(long)s0 * 128 + l2];
        const float a0 = alpha[e * 4 + h];
        const float dn0 = denom[(long)d0 * 4 + h];
        const float an0 = a0 / (dn0 + 1e-16f);
        const float e0a = __uint_as_float(u0 << 16);
        const float e0b = __uint_as_float(u0 & 0xffff0000u);
        atomicAdd(&out[(long)d0 * 128 + l2],     (v0.x + e0a) * an0);
        atomicAdd(&out[(long)d0 * 128 + l2 + 1], (v0.y + e0b) * an0);
    }
}

// ---------------------------------------------------------------------------
// Workspace layout (float offsets):
//   Qn    [N,128]  @ 0
//   Kn    [N,128]  @ 12,800,000
//   Vn    [N,128]  @ 25,600,000
//   alpha [E,4]    @ 38,400,000   (holds exp values)
//   denom [N,4]    @ 40,400,000
//   Ee bf16 [E,128]@ byte 163,200,032
// ---------------------------------------------------------------------------
extern "C" void kernel_launch(void* const* d_in, const int* in_sizes, int n_in,
                              void* d_out, int out_size, void* d_ws, size_t ws_size,
                              hipStream_t stream)
{
    const float* x  = (const float*)d_in[0];
    const int*   ei = (const int*)d_in[1];
    const float* ea = (const float*)d_in[2];
    const float* Wq = (const float*)d_in[3];
    const float* bq = (const float*)d_in[4];
    const float* Wk = (const float*)d_in[5];
    const float* bk = (const float*)d_in[6];
    const float* Wv = (const float*)d_in[7];
    const float* bv = (const float*)d_in[8];
    const float* We = (const float*)d_in[9];
    const float* Ws = (const float*)d_in[10];
    const float* bs = (const float*)d_in[11];
    float* out = (float*)d_out;

    float* ws    = (float*)d_ws;
    float* Qn    = ws;
    float* Kn    = ws + 12800000;
    float* Vn    = ws + 25600000;
    float* alpha = ws + 38400000;
    float* denom = ws + 40400000;
    unsigned short* Ee = (unsigned short*)((char*)d_ws + 163200032);

    hipMemsetAsync(denom, 0, 400000 * sizeof(float), stream);

    node_proj_kernel<<<782 * 4, 256, 0, stream>>>(x, Wq, bq, Wk, bk, Wv, bv, Ws, bs,
                                                  Qn, Kn, Vn, out);
    ee_gemm_kernel<<<(N_EDGES + 127) / 128, 256, 0, stream>>>(ea, We, Ee);
    edge_alpha_kernel<<<2048, 256, 0, stream>>>(ei, Ee, Qn, Kn, alpha, denom);
    edge_msg_kernel<<<2048, 256, 0, stream>>>(ei, Ee, Vn, alpha, denom, out);
}

// Round 4
// 683.064 us; speedup vs baseline: 2.7401x; 1.4152x over previous
//
#include <hip/hip_runtime.h>
#include <hip/hip_bf16.h>
#include <math.h>

#define N_NODES 100000
#define N_EDGES 500000
#define M0 8.0f
#define INV_SQRT32 0.17677669529663687f
#define NB_SCAN 98   // ceil(100000/1024)

static __device__ __forceinline__ unsigned short f2bf(float f) {
    __hip_bfloat16 h = __float2bfloat16(f);
    return *(unsigned short*)&h;
}

// ---------------------------------------------------------------------------
// K1: LDS-tiled fp32 GEMM (transposed LDS, ds_read_b128). Unchanged from R3.
// ---------------------------------------------------------------------------
__global__ __launch_bounds__(256) void node_proj_kernel(
    const float* __restrict__ x,
    const float* __restrict__ Wq, const float* __restrict__ bq,
    const float* __restrict__ Wk, const float* __restrict__ bk,
    const float* __restrict__ Wv, const float* __restrict__ bv,
    const float* __restrict__ Ws, const float* __restrict__ bs,
    float* __restrict__ Qn, float* __restrict__ Kn, float* __restrict__ Vn,
    float* __restrict__ out)
{
    __shared__ float xsT[32][132];
    __shared__ float wtT[32][132];

    const int t = threadIdx.x;
    const int rb = blockIdx.x >> 2;
    const int cb = blockIdx.x & 3;
    const long r0 = (long)rb * 128;

    const float* W    = (cb == 0) ? Wq : (cb == 1) ? Wk : (cb == 2) ? Wv : Ws;
    const float* bias = (cb == 0) ? bq : (cb == 1) ? bk : (cb == 2) ? bv : bs;
    float* dstp       = (cb == 0) ? Qn : (cb == 1) ? Kn : (cb == 2) ? Vn : out;

    const int tx = t & 15;
    const int ty = t >> 4;

    float acc[8][8];
#pragma unroll
    for (int i = 0; i < 8; ++i)
#pragma unroll
        for (int j = 0; j < 8; ++j) acc[i][j] = 0.f;

    for (int kc = 0; kc < 128; kc += 32) {
        __syncthreads();
        for (int i = t; i < 1024; i += 256) {
            const int r = i >> 3;
            const int c4 = (i & 7) * 4;
            const long row = r0 + r;
            float4 xv = (row < N_NODES) ? *(const float4*)&x[row * 128 + kc + c4]
                                        : make_float4(0.f, 0.f, 0.f, 0.f);
            xsT[c4 + 0][r] = xv.x; xsT[c4 + 1][r] = xv.y;
            xsT[c4 + 2][r] = xv.z; xsT[c4 + 3][r] = xv.w;
            float4 wv = *(const float4*)&W[r * 128 + kc + c4];
            wtT[c4 + 0][r] = wv.x; wtT[c4 + 1][r] = wv.y;
            wtT[c4 + 2][r] = wv.z; wtT[c4 + 3][r] = wv.w;
        }
        __syncthreads();
#pragma unroll 4
        for (int k = 0; k < 32; ++k) {
            const float4 a0 = *(const float4*)&xsT[k][ty * 8];
            const float4 a1 = *(const float4*)&xsT[k][ty * 8 + 4];
            const float4 b0 = *(const float4*)&wtT[k][tx * 4];
            const float4 b1 = *(const float4*)&wtT[k][64 + tx * 4];
            const float a[8] = {a0.x, a0.y, a0.z, a0.w, a1.x, a1.y, a1.z, a1.w};
            const float b[8] = {b0.x, b0.y, b0.z, b0.w, b1.x, b1.y, b1.z, b1.w};
#pragma unroll
            for (int i = 0; i < 8; ++i)
#pragma unroll
                for (int j = 0; j < 8; ++j)
                    acc[i][j] = fmaf(a[i], b[j], acc[i][j]);
        }
    }

    float bias0[4], bias1[4];
#pragma unroll
    for (int j = 0; j < 4; ++j) {
        bias0[j] = bias[tx * 4 + j];
        bias1[j] = bias[64 + tx * 4 + j];
    }

#pragma unroll
    for (int i = 0; i < 8; ++i) {
        const long row = r0 + ty * 8 + i;
        if (row < N_NODES) {
            float4 o0 = make_float4(acc[i][0] + bias0[0], acc[i][1] + bias0[1],
                                    acc[i][2] + bias0[2], acc[i][3] + bias0[3]);
            float4 o1 = make_float4(acc[i][4] + bias1[0], acc[i][5] + bias1[1],
                                    acc[i][6] + bias1[2], acc[i][7] + bias1[3]);
            *(float4*)&dstp[row * 128 + tx * 4] = o0;
            *(float4*)&dstp[row * 128 + 64 + tx * 4] = o1;
        }
    }
}

// ---------------------------------------------------------------------------
// K1b: Ee[e,ch] = ea[e,:] . We[ch,:], bf16 out. Unchanged from R3.
// ---------------------------------------------------------------------------
__global__ __launch_bounds__(256) void ee_gemm_kernel(
    const float* __restrict__ ea, const float* __restrict__ We,
    unsigned short* __restrict__ Ee)
{
    __shared__ float easT[32][132];
    __shared__ float wesT[32][132];

    const int t = threadIdx.x;
    const long e0 = (long)blockIdx.x * 128;
    const int tx = t & 15;
    const int ty = t >> 4;

    float acc[8][8];
#pragma unroll
    for (int i = 0; i < 8; ++i)
#pragma unroll
        for (int j = 0; j < 8; ++j) acc[i][j] = 0.f;

    for (int kc = 0; kc < 64; kc += 32) {
        __syncthreads();
        for (int i = t; i < 1024; i += 256) {
            const int r = i >> 3;
            const int c4 = (i & 7) * 4;
            const long e = e0 + r;
            float4 av = (e < N_EDGES) ? *(const float4*)&ea[e * 64 + kc + c4]
                                      : make_float4(0.f, 0.f, 0.f, 0.f);
            easT[c4 + 0][r] = av.x; easT[c4 + 1][r] = av.y;
            easT[c4 + 2][r] = av.z; easT[c4 + 3][r] = av.w;
            float4 wv = *(const float4*)&We[r * 64 + kc + c4];
            wesT[c4 + 0][r] = wv.x; wesT[c4 + 1][r] = wv.y;
            wesT[c4 + 2][r] = wv.z; wesT[c4 + 3][r] = wv.w;
        }
        __syncthreads();
#pragma unroll 4
        for (int k = 0; k < 32; ++k) {
            const float4 a0 = *(const float4*)&easT[k][ty * 8];
            const float4 a1 = *(const float4*)&easT[k][ty * 8 + 4];
            const float4 b0 = *(const float4*)&wesT[k][tx * 4];
            const float4 b1 = *(const float4*)&wesT[k][64 + tx * 4];
            const float a[8] = {a0.x, a0.y, a0.z, a0.w, a1.x, a1.y, a1.z, a1.w};
            const float b[8] = {b0.x, b0.y, b0.z, b0.w, b1.x, b1.y, b1.z, b1.w};
#pragma unroll
            for (int i = 0; i < 8; ++i)
#pragma unroll
                for (int j = 0; j < 8; ++j)
                    acc[i][j] = fmaf(a[i], b[j], acc[i][j]);
        }
    }

#pragma unroll
    for (int i = 0; i < 8; ++i) {
        const long e = e0 + ty * 8 + i;
        if (e < N_EDGES) {
            ushort4 u0, u1;
            u0.x = f2bf(acc[i][0]); u0.y = f2bf(acc[i][1]);
            u0.z = f2bf(acc[i][2]); u0.w = f2bf(acc[i][3]);
            u1.x = f2bf(acc[i][4]); u1.y = f2bf(acc[i][5]);
            u1.z = f2bf(acc[i][6]); u1.w = f2bf(acc[i][7]);
            *(ushort4*)&Ee[e * 128 + tx * 4] = u0;
            *(ushort4*)&Ee[e * 128 + 64 + tx * 4] = u1;
        }
    }
}

// ---------------------------------------------------------------------------
// CSR build: histogram -> 2-level exclusive scan -> fill.
// cursor[] doubles as the degree array (hist) and the running cursor (fill).
// ---------------------------------------------------------------------------
__global__ __launch_bounds__(256) void csr_hist_kernel(
    const int* __restrict__ ei, int* __restrict__ cursor)
{
    const int e = blockIdx.x * 256 + threadIdx.x;
    if (e >= N_EDGES) return;
    atomicAdd(&cursor[ei[N_EDGES + e]], 1);
}

__global__ __launch_bounds__(256) void csr_scan_part_kernel(
    const int* __restrict__ deg, int* __restrict__ bsum)
{
    __shared__ int red[256];
    const int t = threadIdx.x;
    const int i0 = blockIdx.x * 1024 + t * 4;
    int s = 0;
#pragma unroll
    for (int j = 0; j < 4; ++j) {
        const int n = i0 + j;
        if (n < N_NODES) s += deg[n];
    }
    red[t] = s;
    __syncthreads();
    for (int o = 128; o > 0; o >>= 1) {
        if (t < o) red[t] += red[t + o];
        __syncthreads();
    }
    if (t == 0) bsum[blockIdx.x] = red[0];
}

__global__ void csr_scan_top_kernel(int* __restrict__ bsum, int* __restrict__ csr_off)
{
    if (threadIdx.x == 0 && blockIdx.x == 0) {
        int run = 0;
        for (int b = 0; b < NB_SCAN; ++b) {
            const int v = bsum[b];
            bsum[b] = run;
            run += v;
        }
        csr_off[N_NODES] = run;   // == N_EDGES
    }
}

__global__ __launch_bounds__(256) void csr_scan_final_kernel(
    const int* __restrict__ bsum, int* __restrict__ cursor,
    int* __restrict__ csr_off)
{
    __shared__ int ts[256];
    const int t = threadIdx.x;
    const int i0 = blockIdx.x * 1024 + t * 4;
    int d[4];
    int s = 0;
#pragma unroll
    for (int j = 0; j < 4; ++j) {
        const int n = i0 + j;
        d[j] = (n < N_NODES) ? cursor[n] : 0;
        s += d[j];
    }
    ts[t] = s;
    __syncthreads();
    for (int o = 1; o < 256; o <<= 1) {
        int v = (t >= o) ? ts[t - o] : 0;
        __syncthreads();
        ts[t] += v;
        __syncthreads();
    }
    int run = bsum[blockIdx.x] + ts[t] - s;   // exclusive offset for first elem
#pragma unroll
    for (int j = 0; j < 4; ++j) {
        const int n = i0 + j;
        if (n < N_NODES) {
            csr_off[n] = run;
            cursor[n] = run;
            run += d[j];
        }
    }
}

__global__ __launch_bounds__(256) void csr_fill_kernel(
    const int* __restrict__ ei, int* __restrict__ cursor,
    int* __restrict__ csr_eid, int* __restrict__ csr_src)
{
    const int e = blockIdx.x * 256 + threadIdx.x;
    if (e >= N_EDGES) return;
    const int dst = ei[N_EDGES + e];
    const int pos = atomicAdd(&cursor[dst], 1);
    csr_eid[pos] = e;
    csr_src[pos] = ei[e];
}

// ---------------------------------------------------------------------------
// Fused attention gather: one wave per node. Lane owns channels {2l,2l+1},
// head h=l>>4. Pass 1: softmax denom in registers. Pass 2: recompute p
// (L1/L2-hot re-reads) and accumulate (Vn[src]+Ee)*alpha into registers.
// Single float2 store. Zero output atomics.
// ---------------------------------------------------------------------------
__global__ __launch_bounds__(256) void fused_attn_kernel(
    const int* __restrict__ csr_off, const int* __restrict__ csr_eid,
    const int* __restrict__ csr_src, const unsigned short* __restrict__ Ee,
    const float* __restrict__ Qn, const float* __restrict__ Kn,
    const float* __restrict__ Vn, float* __restrict__ out)
{
    const int lane = threadIdx.x & 63;
    const int l2 = lane * 2;
    const long n = (long)blockIdx.x * 4 + (threadIdx.x >> 6);

    const int off0 = csr_off[n];
    const int off1 = csr_off[n + 1];
    const float2 q = *(const float2*)&Qn[n * 128 + l2];
    float2 acc = *(const float2*)&out[n * 128 + l2];

    float dsum = 0.f;
    for (int base = off0; base < off1; base += 64) {
        const int cnt = min(64, off1 - base);
        int eid = 0, src = 0;
        if (base + lane < off1) {
            eid = csr_eid[base + lane];
            src = csr_src[base + lane];
        }
        for (int j = 0; j < cnt; ++j) {
            const long e = __shfl(eid, j, 64);
            const long s = __shfl(src, j, 64);
            const unsigned u = *(const unsigned*)&Ee[e * 128 + l2];
            const float2 k = *(const float2*)&Kn[s * 128 + l2];
            float p = q.x * (k.x + __uint_as_float(u << 16)) +
                      q.y * (k.y + __uint_as_float(u & 0xffff0000u));
#pragma unroll
            for (int o = 1; o < 16; o <<= 1) p += __shfl_xor(p, o, 64);
            dsum += __expf(p * INV_SQRT32 - M0);
        }
    }
    const float rd = 1.f / (dsum + 1e-16f);

    for (int base = off0; base < off1; base += 64) {
        const int cnt = min(64, off1 - base);
        int eid = 0, src = 0;
        if (base + lane < off1) {
            eid = csr_eid[base + lane];
            src = csr_src[base + lane];
        }
        for (int j = 0; j < cnt; ++j) {
            const long e = __shfl(eid, j, 64);
            const long s = __shfl(src, j, 64);
            const unsigned u = *(const unsigned*)&Ee[e * 128 + l2];
            const float2 k = *(const float2*)&Kn[s * 128 + l2];
            const float ea0 = __uint_as_float(u << 16);
            const float ea1 = __uint_as_float(u & 0xffff0000u);
            float p = q.x * (k.x + ea0) + q.y * (k.y + ea1);
#pragma unroll
            for (int o = 1; o < 16; o <<= 1) p += __shfl_xor(p, o, 64);
            const float an = __expf(p * INV_SQRT32 - M0) * rd;
            const float2 v = *(const float2*)&Vn[s * 128 + l2];
            acc.x = fmaf(v.x + ea0, an, acc.x);
            acc.y = fmaf(v.y + ea1, an, acc.y);
        }
    }
    *(float2*)&out[n * 128 + l2] = acc;
}

// ---------------------------------------------------------------------------
// Workspace layout (int/float offsets):
//   Qn      [N,128]   @ 0
//   Kn      [N,128]   @ 12,800,000
//   Vn      [N,128]   @ 25,600,000
//   csr_off [N+1]     @ 38,400,000  (int)
//   cursor  [N]       @ 38,500,004  (int)
//   csr_eid [E]       @ 38,600,004  (int)
//   csr_src [E]       @ 39,100,004  (int)
//   bsum    [98]      @ 39,600,004  (int)
//   Ee bf16 [E,128]   @ byte 163,200,032
// ---------------------------------------------------------------------------
extern "C" void kernel_launch(void* const* d_in, const int* in_sizes, int n_in,
                              void* d_out, int out_size, void* d_ws, size_t ws_size,
                              hipStream_t stream)
{
    const float* x  = (const float*)d_in[0];
    const int*   ei = (const int*)d_in[1];
    const float* ea = (const float*)d_in[2];
    const float* Wq = (const float*)d_in[3];
    const float* bq = (const float*)d_in[4];
    const float* Wk = (const float*)d_in[5];
    const float* bk = (const float*)d_in[6];
    const float* Wv = (const float*)d_in[7];
    const float* bv = (const float*)d_in[8];
    const float* We = (const float*)d_in[9];
    const float* Ws = (const float*)d_in[10];
    const float* bs = (const float*)d_in[11];
    float* out = (float*)d_out;

    float* ws = (float*)d_ws;
    float* Qn = ws;
    float* Kn = ws + 12800000;
    float* Vn = ws + 25600000;
    int* csr_off = (int*)(ws + 38400000);
    int* cursor  = (int*)(ws + 38500004);
    int* csr_eid = (int*)(ws + 38600004);
    int* csr_src = (int*)(ws + 39100004);
    int* bsum    = (int*)(ws + 39600004);
    unsigned short* Ee = (unsigned short*)((char*)d_ws + 163200032);

    hipMemsetAsync(cursor, 0, N_NODES * sizeof(int), stream);

    node_proj_kernel<<<782 * 4, 256, 0, stream>>>(x, Wq, bq, Wk, bk, Wv, bv, Ws, bs,
                                                  Qn, Kn, Vn, out);
    ee_gemm_kernel<<<(N_EDGES + 127) / 128, 256, 0, stream>>>(ea, We, Ee);

    csr_hist_kernel<<<(N_EDGES + 255) / 256, 256, 0, stream>>>(ei, cursor);
    csr_scan_part_kernel<<<NB_SCAN, 256, 0, stream>>>(cursor, bsum);
    csr_scan_top_kernel<<<1, 64, 0, stream>>>(bsum, csr_off);
    csr_scan_final_kernel<<<NB_SCAN, 256, 0, stream>>>(bsum, cursor, csr_off);
    csr_fill_kernel<<<(N_EDGES + 255) / 256, 256, 0, stream>>>(ei, cursor, csr_eid, csr_src);

    fused_attn_kernel<<<25000, 256, 0, stream>>>(csr_off, csr_eid, csr_src, Ee,
                                                 Qn, Kn, Vn, out);
}